// Round 4
// baseline (2347.955 us; speedup 1.0000x reference)
//
#include <hip/hip_runtime.h>
#include <math.h>

#define N_NODES 50000
#define N_EDGES 1600000
#define F_IN 128
#define C 64
#define EF 64
#define N_GRAPHS 512
#define MLP_DIM 128
#define N_CLASSES 10
#define EPS 1e-5f
#define NB 196            // coarse buckets: dst>>8, 256 nodes each (196*256 >= 50000)
#define CHUNK 4096        // edges per pass-1 block
#define NSLICE 8          // bn-stat atomic slices (de-contend)

typedef __attribute__((ext_vector_type(8))) short short8;   // 8 x bf16 (4 VGPRs)
typedef __attribute__((ext_vector_type(4))) float floatx4;  // MFMA acc
typedef __attribute__((ext_vector_type(2))) float floatx2;  // for v_pk_add_f32
typedef __attribute__((ext_vector_type(4))) unsigned uintx4;

__device__ __forceinline__ unsigned pack2bf(float a, float b) {
    // round-half-up f32->bf16 pair (a=low, b=high) via v_perm_b32
    return __builtin_amdgcn_perm(__float_as_uint(b) + 0x8000u,
                                 __float_as_uint(a) + 0x8000u, 0x07060302u);
}

// ==================== sort pass 0: per-bucket edge counts ====================
__global__ __launch_bounds__(256) void precount_kernel(const int* __restrict__ dst,
                                                       int* __restrict__ bucket_cnt) {
    __shared__ int lc[NB];
    int tid = threadIdx.x;
    for (int i = tid; i < NB; i += 256) lc[i] = 0;
    __syncthreads();
    for (int e = blockIdx.x * 256 + tid; e < N_EDGES; e += gridDim.x * 256)
        atomicAdd(&lc[dst[e] >> 8], 1);
    __syncthreads();
    for (int i = tid; i < NB; i += 256)
        if (lc[i]) atomicAdd(&bucket_cnt[i], lc[i]);
}

// exclusive scan of bucket counts -> bucket_start[0..NB], gcursor
__global__ void bucket_scan_kernel(const int* __restrict__ bucket_cnt,
                                   int* __restrict__ bucket_start, int* __restrict__ gcur) {
    __shared__ int a[256];
    int tid = threadIdx.x;
    int v = (tid < NB) ? bucket_cnt[tid] : 0;
    a[tid] = v;
    __syncthreads();
    for (int off = 1; off < 256; off <<= 1) {
        int t = (tid >= off) ? a[tid - off] : 0;
        __syncthreads();
        a[tid] += t;
        __syncthreads();
    }
    int excl = a[tid] - v;
    if (tid < NB) { bucket_start[tid] = excl; gcur[tid] = excl; }
    if (tid == NB - 1) bucket_start[NB] = excl + v;
}

// ==================== sort pass 1: bin edges into coarse buckets ====================
__global__ __launch_bounds__(256) void pass1_kernel(const int* __restrict__ src,
                                                    const int* __restrict__ dst,
                                                    int* __restrict__ gcur,
                                                    unsigned* __restrict__ keys) {
    __shared__ int lcnt[NB], lbase[NB], lcnt2[NB];
    int tid = threadIdx.x;
    int e0 = blockIdx.x * CHUNK;
    unsigned k[CHUNK / 256];
    int bk[CHUNK / 256];
    for (int i = tid; i < NB; i += 256) lcnt[i] = 0;
    __syncthreads();
#pragma unroll
    for (int i = 0; i < CHUNK / 256; i++) {
        int e = e0 + i * 256 + tid;
        if (e < N_EDGES) {
            int d = dst[e];
            k[i] = ((unsigned)d << 16) | (unsigned)src[e];
            bk[i] = d >> 8;
            atomicAdd(&lcnt[bk[i]], 1);
        } else bk[i] = -1;
    }
    __syncthreads();
    for (int i = tid; i < NB; i += 256) {
        int c = lcnt[i];
        lbase[i] = c ? atomicAdd(&gcur[i], c) : 0;
        lcnt2[i] = 0;
    }
    __syncthreads();
#pragma unroll
    for (int i = 0; i < CHUNK / 256; i++) {
        if (bk[i] >= 0) {
            int r = atomicAdd(&lcnt2[bk[i]], 1);
            keys[lbase[bk[i]] + r] = k[i];
        }
    }
}

// ==================== per-node degree + per-bucket padded sums ====================
__global__ __launch_bounds__(256) void node_count_kernel(const unsigned* __restrict__ keys,
                                                         const int* __restrict__ bucket_start,
                                                         int* __restrict__ cnt,
                                                         int* __restrict__ bsum) {
    __shared__ int lc[256], rs[256];
    int tid = threadIdx.x, b = blockIdx.x;
    lc[tid] = 0;
    __syncthreads();
    int beg = bucket_start[b], end = bucket_start[b + 1];
    for (int p = beg + tid; p < end; p += 256)
        atomicAdd(&lc[(keys[p] >> 16) & 255], 1);
    __syncthreads();
    int node = b * 256 + tid;
    int c = (node < N_NODES) ? lc[tid] : 0;
    if (node < N_NODES) cnt[node] = c;
    rs[tid] = (c + 15) & ~15;
    __syncthreads();
    for (int off = 128; off > 0; off >>= 1) {
        if (tid < off) rs[tid] += rs[tid + off];
        __syncthreads();
    }
    if (tid == 0) bsum[b] = rs[0];
}

// exclusive scan of padded bucket sums -> bbase; writes row_start[N_NODES]
__global__ void pscan_kernel(const int* __restrict__ bsum, int* __restrict__ bbase,
                             int* __restrict__ row_start) {
    __shared__ int a[256];
    int tid = threadIdx.x;
    int v = (tid < NB) ? bsum[tid] : 0;
    a[tid] = v;
    __syncthreads();
    for (int off = 1; off < 256; off <<= 1) {
        int t = (tid >= off) ? a[tid - off] : 0;
        __syncthreads();
        a[tid] += t;
        __syncthreads();
    }
    int excl = a[tid] - v;
    if (tid < NB) bbase[tid] = excl;
    if (tid == NB - 1) row_start[N_NODES] = excl + v;
}

// ==================== pass 2: local scan -> row_start, block-local scatter + pad fill ============
__global__ __launch_bounds__(256) void pass2_kernel(const unsigned* __restrict__ keys,
                                                    const int* __restrict__ bucket_start,
                                                    const int* __restrict__ cnt,
                                                    const int* __restrict__ bbase,
                                                    int* __restrict__ row_start,
                                                    unsigned short* __restrict__ sorted_src) {
    __shared__ int loc[256], rs[256], cur[256];
    int tid = threadIdx.x, b = blockIdx.x;
    int node = b * 256 + tid;
    int c = (node < N_NODES) ? cnt[node] : 0;
    int pc = (c + 15) & ~15;
    loc[tid] = pc;
    cur[tid] = 0;
    __syncthreads();
    for (int off = 1; off < 256; off <<= 1) {
        int t = (tid >= off) ? loc[tid - off] : 0;
        __syncthreads();
        loc[tid] += t;
        __syncthreads();
    }
    int myrs = bbase[b] + loc[tid] - pc;  // exclusive
    rs[tid] = myrs;
    if (node < N_NODES) row_start[node] = myrs;
    __syncthreads();
    int beg = bucket_start[b], end = bucket_start[b + 1];
    for (int p = beg + tid; p < end; p += 256) {
        unsigned k = keys[p];
        int lidx = (k >> 16) & 255;
        int r = atomicAdd(&cur[lidx], 1);
        sorted_src[rs[lidx] + r] = (unsigned short)(k & 0xFFFFu);
    }
    __syncthreads();
    if (node < N_NODES) {
        int deg = cur[tid];
        if (deg > 0) {
            unsigned short s0 = sorted_src[myrs];
            for (int p = myrs + deg; p < myrs + pc; p++) sorted_src[p] = s0;  // max idempotent
        }
    }
}

// ============================ fc0: h0 = x @ fc0_w + fc0_b  (+ BN stats for block 0) ============
__global__ __launch_bounds__(256) void fc0_kernel(const float* __restrict__ x,
                                                  const float* __restrict__ w,
                                                  const float* __restrict__ b,
                                                  float* __restrict__ h0,
                                                  float* __restrict__ bns) {
    __shared__ float wl[F_IN * C];  // 32 KiB
    __shared__ __align__(16) float xr[4][F_IN];
    __shared__ float r1[4][64], r2[4][64];
    int tid = threadIdx.x, lane = tid & 63, wid = tid >> 6;
    for (int i = tid; i < F_IN * C; i += 256) wl[i] = w[i];
    __syncthreads();
    float bj = b[lane];
    float s1 = 0.f, s2 = 0.f;
    for (int n = blockIdx.x * 4 + wid; n < N_NODES; n += gridDim.x * 4) {
        xr[wid][lane]      = x[n * F_IN + lane];
        xr[wid][64 + lane] = x[n * F_IN + 64 + lane];
        const float4* x4 = (const float4*)xr[wid];
        float a0 = 0, a1 = 0, a2 = 0, a3 = 0;
#pragma unroll
        for (int k4 = 0; k4 < F_IN / 4; k4++) {
            float4 hv = x4[k4];
            a0 = fmaf(hv.x, wl[(4 * k4 + 0) * C + lane], a0);
            a1 = fmaf(hv.y, wl[(4 * k4 + 1) * C + lane], a1);
            a2 = fmaf(hv.z, wl[(4 * k4 + 2) * C + lane], a2);
            a3 = fmaf(hv.w, wl[(4 * k4 + 3) * C + lane], a3);
        }
        float v = (a0 + a1) + (a2 + a3) + bj;
        h0[n * C + lane] = v;
        s1 += v; s2 += v * v;
    }
    r1[wid][lane] = s1; r2[wid][lane] = s2;
    __syncthreads();
    if (tid < 64) {
        float a  = r1[0][tid] + r1[1][tid] + r1[2][tid] + r1[3][tid];
        float c2 = r2[0][tid] + r2[1][tid] + r2[2][tid] + r2[3][tid];
        int sl = blockIdx.x & (NSLICE - 1);
        atomicAdd(&bns[sl * 128 + tid], a);
        atomicAdd(&bns[sl * 128 + 64 + tid], c2);
    }
}

// ===== fold BN into effective edge-MLP layer-1 weights: WA = scale*(w1a-w1b), WB = scale*w1b =====
__global__ void prep_kernel(const float* __restrict__ bns, const float* __restrict__ g,
                            const float* __restrict__ bb, const float* __restrict__ w1,
                            const float* __restrict__ b1, float* __restrict__ WA,
                            float* __restrict__ WB, float* __restrict__ cAB) {
    __shared__ float scale[64], shift[64];
    int j = threadIdx.x;  // 64 threads
    float s1v = 0.f, s2v = 0.f;
#pragma unroll
    for (int s = 0; s < NSLICE; s++) { s1v += bns[s * 128 + j]; s2v += bns[s * 128 + 64 + j]; }
    float mu  = s1v * (1.0f / N_NODES);
    float var = s2v * (1.0f / N_NODES) - mu * mu;
    float sc  = g[j] * rsqrtf(var + EPS);
    scale[j] = sc;
    shift[j] = bb[j] - mu * sc;
    __syncthreads();
    float ca = b1[j], cb = 0.f;
    for (int k = 0; k < 64; k++) {
        float wa_ = w1[k * EF + j];
        float wb_ = w1[(64 + k) * EF + j];
        float wd  = wa_ - wb_;
        WA[k * 64 + j] = scale[k] * wd;
        WB[k * 64 + j] = scale[k] * wb_;
        ca += shift[k] * wd;
        cb += shift[k] * wb_;
    }
    cAB[j] = ca;
    cAB[64 + j] = cb;
}

// ============ per-node tables: A = h@WA + cA (f32), B = h@WB + cB (bf16) ============
__global__ __launch_bounds__(256) void ab_kernel(const float* __restrict__ h, int ldh,
                                                 const float* __restrict__ WA,
                                                 const float* __restrict__ WB,
                                                 const float* __restrict__ cAB,
                                                 float* __restrict__ A,
                                                 unsigned short* __restrict__ Bb) {
    __shared__ float wal[64 * 64], wbl[64 * 64];  // 32 KiB
    __shared__ __align__(16) float hr[4][64];
    int tid = threadIdx.x, lane = tid & 63, wid = tid >> 6;
    for (int i = tid; i < 4096; i += 256) { wal[i] = WA[i]; wbl[i] = WB[i]; }
    __syncthreads();
    float ca = cAB[lane], cb = cAB[64 + lane];
    for (int n = blockIdx.x * 4 + wid; n < N_NODES; n += gridDim.x * 4) {
        hr[wid][lane] = h[(size_t)n * ldh + lane];
        const float4* h4 = (const float4*)hr[wid];
        float accA = ca, accB = cb;
#pragma unroll
        for (int k4 = 0; k4 < 16; k4++) {
            float4 hv = h4[k4];
            accA = fmaf(hv.x, wal[(4 * k4 + 0) * 64 + lane], accA);
            accB = fmaf(hv.x, wbl[(4 * k4 + 0) * 64 + lane], accB);
            accA = fmaf(hv.y, wal[(4 * k4 + 1) * 64 + lane], accA);
            accB = fmaf(hv.y, wbl[(4 * k4 + 1) * 64 + lane], accB);
            accA = fmaf(hv.z, wal[(4 * k4 + 2) * 64 + lane], accA);
            accB = fmaf(hv.z, wbl[(4 * k4 + 2) * 64 + lane], accB);
            accA = fmaf(hv.w, wal[(4 * k4 + 3) * 64 + lane], accA);
            accB = fmaf(hv.w, wbl[(4 * k4 + 3) * 64 + lane], accB);
        }
        A[n * 64 + lane] = accA;
        Bb[n * 64 + lane] = (unsigned short)((__float_as_uint(accB) + 0x8000u) >> 16);
    }
}

// ============ EdgeConv via MFMA, dynamic node scheduling, fused next-block BN stats ============
__global__ __launch_bounds__(256) void edge_mfma_kernel(
        const float* __restrict__ A, const unsigned short* __restrict__ Bb,
        const int* __restrict__ row_start, const unsigned short* __restrict__ sorted_src,
        const float* __restrict__ w2, const float* __restrict__ b2,
        float* __restrict__ cat, int colofs,
        int* __restrict__ wcur, float* __restrict__ bnsNext) {
    __shared__ float r1[4][64], r2[4][64];
    int tid = threadIdx.x, lane = tid & 63, wid = tid >> 6;
    int kq = (lane >> 4) * 8;  // this lane's k-offset within each 32-chunk
    int cl = lane & 15;

    // w2 fragments, wave-invariant, held in registers (16 VGPRs)
    short8 bfr[2][4];
#pragma unroll
    for (int kh = 0; kh < 2; kh++)
#pragma unroll
        for (int cb = 0; cb < 4; cb++) {
            union { short8 s; unsigned u[4]; } f;
#pragma unroll
            for (int j = 0; j < 4; j++) {
                float w0 = w2[(kh * 32 + kq + 2 * j) * 64 + cb * 16 + cl];
                float w1 = w2[(kh * 32 + kq + 2 * j + 1) * 64 + cb * 16 + cl];
                f.u[j] = pack2bf(w0, w1);
            }
            bfr[kh][cb] = f.s;
        }
    float b2j = b2[lane];
    float s1 = 0.f, s2 = 0.f;
    (void)wid;

    for (;;) {
        int n;
        if (lane == 0) n = atomicAdd(wcur, 1);
        n = __builtin_amdgcn_readfirstlane(n);
        if (n >= N_NODES) break;
        int beg = row_start[n], end = row_start[n + 1];
        const float* arow = A + (size_t)n * 64 + kq;
        floatx4 t0 = *(const floatx4*)(arow);
        floatx4 t1 = *(const floatx4*)(arow + 4);
        floatx4 t2 = *(const floatx4*)(arow + 32);
        floatx4 t3 = *(const floatx4*)(arow + 36);
        floatx2 aj0[4], aj1[4];
        aj0[0] = floatx2{t0.x, t0.y}; aj0[1] = floatx2{t0.z, t0.w};
        aj0[2] = floatx2{t1.x, t1.y}; aj0[3] = floatx2{t1.z, t1.w};
        aj1[0] = floatx2{t2.x, t2.y}; aj1[1] = floatx2{t2.z, t2.w};
        aj1[2] = floatx2{t3.x, t3.y}; aj1[3] = floatx2{t3.z, t3.w};
        floatx4 rmax0 = {-INFINITY, -INFINITY, -INFINITY, -INFINITY};
        floatx4 rmax1 = rmax0, rmax2 = rmax0, rmax3 = rmax0;

        for (int p0 = beg; p0 < end; p0 += 16) {
            int srcm = sorted_src[p0 + cl];  // edge row m = cl for this lane
            const unsigned short* brow = Bb + (size_t)srcm * 64 + kq;
            uintx4 u0 = *(const uintx4*)(brow);       // bf16 x8: k = kq..kq+7
            uintx4 u1 = *(const uintx4*)(brow + 32);  // bf16 x8: k = 32+kq..32+kq+7
            union { short8 s; unsigned u[4]; } a0, a1;
#pragma unroll
            for (int j = 0; j < 4; j++) {
                floatx2 s0 = floatx2{__uint_as_float(u0[j] << 16),
                                     __uint_as_float(u0[j] & 0xFFFF0000u)} + aj0[j];
                floatx2 sx = floatx2{__uint_as_float(u1[j] << 16),
                                     __uint_as_float(u1[j] & 0xFFFF0000u)} + aj1[j];
                a0.u[j] = pack2bf(fmaxf(s0.x, 0.f), fmaxf(s0.y, 0.f));
                a1.u[j] = pack2bf(fmaxf(sx.x, 0.f), fmaxf(sx.y, 0.f));
            }

            floatx4 acc0 = {0.f, 0.f, 0.f, 0.f}, acc1 = acc0, acc2 = acc0, acc3 = acc0;
            acc0 = __builtin_amdgcn_mfma_f32_16x16x32_bf16(a0.s, bfr[0][0], acc0, 0, 0, 0);
            acc1 = __builtin_amdgcn_mfma_f32_16x16x32_bf16(a0.s, bfr[0][1], acc1, 0, 0, 0);
            acc2 = __builtin_amdgcn_mfma_f32_16x16x32_bf16(a0.s, bfr[0][2], acc2, 0, 0, 0);
            acc3 = __builtin_amdgcn_mfma_f32_16x16x32_bf16(a0.s, bfr[0][3], acc3, 0, 0, 0);
            acc0 = __builtin_amdgcn_mfma_f32_16x16x32_bf16(a1.s, bfr[1][0], acc0, 0, 0, 0);
            acc1 = __builtin_amdgcn_mfma_f32_16x16x32_bf16(a1.s, bfr[1][1], acc1, 0, 0, 0);
            acc2 = __builtin_amdgcn_mfma_f32_16x16x32_bf16(a1.s, bfr[1][2], acc2, 0, 0, 0);
            acc3 = __builtin_amdgcn_mfma_f32_16x16x32_bf16(a1.s, bfr[1][3], acc3, 0, 0, 0);

            rmax0.x = fmaxf(rmax0.x, acc0.x); rmax0.y = fmaxf(rmax0.y, acc0.y);
            rmax0.z = fmaxf(rmax0.z, acc0.z); rmax0.w = fmaxf(rmax0.w, acc0.w);
            rmax1.x = fmaxf(rmax1.x, acc1.x); rmax1.y = fmaxf(rmax1.y, acc1.y);
            rmax1.z = fmaxf(rmax1.z, acc1.z); rmax1.w = fmaxf(rmax1.w, acc1.w);
            rmax2.x = fmaxf(rmax2.x, acc2.x); rmax2.y = fmaxf(rmax2.y, acc2.y);
            rmax2.z = fmaxf(rmax2.z, acc2.z); rmax2.w = fmaxf(rmax2.w, acc2.w);
            rmax3.x = fmaxf(rmax3.x, acc3.x); rmax3.y = fmaxf(rmax3.y, acc3.y);
            rmax3.z = fmaxf(rmax3.z, acc3.z); rmax3.w = fmaxf(rmax3.w, acc3.w);
        }

        float v0 = fmaxf(fmaxf(rmax0.x, rmax0.y), fmaxf(rmax0.z, rmax0.w));
        float v1 = fmaxf(fmaxf(rmax1.x, rmax1.y), fmaxf(rmax1.z, rmax1.w));
        float v2 = fmaxf(fmaxf(rmax2.x, rmax2.y), fmaxf(rmax2.z, rmax2.w));
        float v3 = fmaxf(fmaxf(rmax3.x, rmax3.y), fmaxf(rmax3.z, rmax3.w));
        v0 = fmaxf(v0, __shfl_xor(v0, 16)); v0 = fmaxf(v0, __shfl_xor(v0, 32));
        v1 = fmaxf(v1, __shfl_xor(v1, 16)); v1 = fmaxf(v1, __shfl_xor(v1, 32));
        v2 = fmaxf(v2, __shfl_xor(v2, 16)); v2 = fmaxf(v2, __shfl_xor(v2, 32));
        v3 = fmaxf(v3, __shfl_xor(v3, 16)); v3 = fmaxf(v3, __shfl_xor(v3, 32));
        float vs = (lane & 32) ? ((lane & 16) ? v3 : v2) : ((lane & 16) ? v1 : v0);
        float v = fmaxf(vs + b2j, 0.f);  // -inf (empty node) -> 0; folds where(isfinite)+relu
        cat[(size_t)n * 192 + colofs + lane] = v;
        s1 += v; s2 += v * v;
    }

    if (bnsNext) {
        int wd = tid >> 6;
        r1[wd][lane] = s1; r2[wd][lane] = s2;
        __syncthreads();
        if (tid < 64) {
            float a  = r1[0][tid] + r1[1][tid] + r1[2][tid] + r1[3][tid];
            float c2 = r2[0][tid] + r2[1][tid] + r2[2][tid] + r2[3][tid];
            int sl = blockIdx.x & (NSLICE - 1);
            atomicAdd(&bnsNext[sl * 128 + tid], a);
            atomicAdd(&bnsNext[sl * 128 + 64 + tid], c2);
        }
    }
}

// ============================ fused graph mean pool + MLP head + log_softmax ============================
__global__ __launch_bounds__(192) void poolhead_kernel(const float* __restrict__ cat,
                                                       const int* __restrict__ batch,
                                                       const float* __restrict__ fc1w,
                                                       const float* __restrict__ fc1b,
                                                       const float* __restrict__ fc2w,
                                                       const float* __restrict__ fc2b,
                                                       float* __restrict__ out) {
    __shared__ int se[2];
    __shared__ float p[192];
    __shared__ float hid[128];
    __shared__ float z[10];
    __shared__ float lse;
    int g = blockIdx.x, tid = threadIdx.x;  // 192 threads
    if (tid < 2) {
        int target = g + tid;
        int lo = 0, hi = N_NODES;
        while (lo < hi) { int mid = (lo + hi) >> 1; if (batch[mid] < target) lo = mid + 1; else hi = mid; }
        se[tid] = lo;
    }
    __syncthreads();
    int s = se[0], e = se[1];
    float acc = 0.f;
    for (int r = s; r < e; r++) acc += cat[(size_t)r * 192 + tid];
    float denom = (e > s) ? (float)(e - s) : 1.0f;
    p[tid] = acc / denom;
    __syncthreads();
    if (tid < MLP_DIM) {
        float a = fc1b[tid];
        for (int k = 0; k < 192; k++) a = fmaf(p[k], fc1w[k * 128 + tid], a);
        hid[tid] = fmaxf(a, 0.f);
    }
    __syncthreads();
    if (tid < N_CLASSES) {
        float a = fc2b[tid];
        for (int k = 0; k < 128; k++) a = fmaf(hid[k], fc2w[k * 10 + tid], a);
        z[tid] = a;
    }
    __syncthreads();
    if (tid == 0) {
        float m = z[0];
        for (int i = 1; i < 10; i++) m = fmaxf(m, z[i]);
        float sm = 0.f;
        for (int i = 0; i < 10; i++) sm += expf(z[i] - m);
        lse = m + logf(sm);
    }
    __syncthreads();
    if (tid < N_CLASSES) out[g * 10 + tid] = z[tid] - lse;
}

// ============================ launch ============================
extern "C" void kernel_launch(void* const* d_in, const int* in_sizes, int n_in,
                              void* d_out, int out_size, void* d_ws, size_t ws_size,
                              hipStream_t stream) {
    (void)in_sizes; (void)n_in; (void)out_size; (void)ws_size;
    const float* x    = (const float*)d_in[0];
    const int*   ei   = (const int*)d_in[1];
    const int*   batch= (const int*)d_in[2];
    const float* fc0w = (const float*)d_in[3];
    const float* fc0b = (const float*)d_in[4];
    const float* fc1w = (const float*)d_in[5];
    const float* fc1b = (const float*)d_in[6];
    const float* fc2w = (const float*)d_in[7];
    const float* fc2b = (const float*)d_in[8];
    const int* src = ei;
    const int* dst = ei + N_EDGES;
    float* out = (float*)d_out;

    char* w = (char*)d_ws;
    size_t off = 0;
    auto alloc = [&](size_t bytes) -> void* {
        void* p = w + off;
        off = (off + bytes + 255) & ~(size_t)255;
        return p;
    };
    const size_t MAX_PAD_EDGES = (size_t)N_EDGES + 16 * (size_t)N_NODES;

    // zeroed-every-launch block: bucket_cnt | wcur[3] | bns[3][NSLICE][128]
    char* zbase = (char*)alloc(2048 + 3 * NSLICE * 128 * 4);
    int*   bucket_cnt = (int*)zbase;                 // NB ints
    int*   wcur   = (int*)(zbase + 1024);            // 3 ints
    float* bnsAll = (float*)(zbase + 2048);          // 3 * NSLICE * 128 floats
    const size_t ZBYTES = 2048 + 3 * NSLICE * 128 * 4;

    float* cat     = (float*)alloc((size_t)N_NODES * 192 * 4);   // 38.4 MB
    float* h0      = (float*)alloc((size_t)N_NODES * 64 * 4);    // 12.8 MB
    float* Ae      = (float*)alloc((size_t)N_NODES * 64 * 4);    // 12.8 MB
    unsigned short* Be = (unsigned short*)alloc((size_t)N_NODES * 64 * 2);  // 6.4 MB (bf16)
    unsigned* keys = (unsigned*)alloc((size_t)N_EDGES * 4);      // 6.4 MB
    unsigned short* sorted_src = (unsigned short*)alloc(MAX_PAD_EDGES * 2);  // 4.8 MB
    int*   cnt     = (int*)alloc((size_t)N_NODES * 4);
    int*   row_start = (int*)alloc((size_t)(N_NODES + 1) * 4);
    int*   bucket_start = (int*)alloc((NB + 1) * 4);
    int*   gcur    = (int*)alloc(NB * 4);
    int*   bsum    = (int*)alloc(NB * 4);
    int*   bbase   = (int*)alloc(NB * 4);
    float* WA      = (float*)alloc(4096 * 4);
    float* WB      = (float*)alloc(4096 * 4);
    float* cAB     = (float*)alloc(128 * 4);

    hipMemsetAsync(zbase, 0, ZBYTES, stream);

    // --- two-level counting sort: edges -> padded CSR by dst ---
    precount_kernel<<<256, 256, 0, stream>>>(dst, bucket_cnt);
    bucket_scan_kernel<<<1, 256, 0, stream>>>(bucket_cnt, bucket_start, gcur);
    pass1_kernel<<<(N_EDGES + CHUNK - 1) / CHUNK, 256, 0, stream>>>(src, dst, gcur, keys);
    node_count_kernel<<<NB, 256, 0, stream>>>(keys, bucket_start, cnt, bsum);
    pscan_kernel<<<1, 256, 0, stream>>>(bsum, bbase, row_start);
    pass2_kernel<<<NB, 256, 0, stream>>>(keys, bucket_start, cnt, bbase, row_start, sorted_src);

    fc0_kernel<<<1024, 256, 0, stream>>>(x, fc0w, fc0b, h0, bnsAll);

    for (int blk = 0; blk < 3; blk++) {
        const float* g  = (const float*)d_in[9 + 6 * blk];
        const float* bb = (const float*)d_in[10 + 6 * blk];
        const float* w1 = (const float*)d_in[11 + 6 * blk];
        const float* b1 = (const float*)d_in[12 + 6 * blk];
        const float* w2 = (const float*)d_in[13 + 6 * blk];
        const float* b2 = (const float*)d_in[14 + 6 * blk];
        const float* hsrc = (blk == 0) ? h0 : (cat + (blk - 1) * 64);
        int ldh = (blk == 0) ? 64 : 192;

        prep_kernel<<<1, 64, 0, stream>>>(bnsAll + blk * NSLICE * 128, g, bb, w1, b1, WA, WB, cAB);
        ab_kernel<<<1024, 256, 0, stream>>>(hsrc, ldh, WA, WB, cAB, Ae, Be);
        edge_mfma_kernel<<<2048, 256, 0, stream>>>(
            Ae, Be, row_start, sorted_src, w2, b2, cat, blk * 64, wcur + blk,
            (blk < 2) ? (bnsAll + (blk + 1) * NSLICE * 128) : nullptr);
    }

    poolhead_kernel<<<N_GRAPHS, 192, 0, stream>>>(cat, batch, fc1w, fc1b, fc2w, fc2b, out);
}

// Round 5
// 491.319 us; speedup vs baseline: 4.7789x; 4.7789x over previous
//
#include <hip/hip_runtime.h>
#include <math.h>

#define N_NODES 50000
#define N_EDGES 1600000
#define F_IN 128
#define C 64
#define EF 64
#define N_GRAPHS 512
#define MLP_DIM 128
#define N_CLASSES 10
#define EPS 1e-5f
#define NB 196            // coarse buckets: dst>>8, 256 nodes each (196*256 >= 50000)
#define CHUNK 4096        // edges per pass-1 block
#define NSLICE 8          // bn-stat atomic slices (de-contend)

typedef __attribute__((ext_vector_type(8))) short short8;   // 8 x bf16 (4 VGPRs)
typedef __attribute__((ext_vector_type(4))) float floatx4;  // MFMA acc
typedef __attribute__((ext_vector_type(2))) float floatx2;  // v_pk_add_f32 / v_pk_max_f32
typedef __attribute__((ext_vector_type(4))) unsigned uintx4;

__device__ __forceinline__ unsigned pack2bf(float a, float b) {
    // round-half-up f32->bf16 pair (a=low, b=high) via v_perm_b32
    return __builtin_amdgcn_perm(__float_as_uint(b) + 0x8000u,
                                 __float_as_uint(a) + 0x8000u, 0x07060302u);
}

// ==================== sort pass 0: per-bucket edge counts ====================
__global__ __launch_bounds__(256) void precount_kernel(const int* __restrict__ dst,
                                                       int* __restrict__ bucket_cnt) {
    __shared__ int lc[NB];
    int tid = threadIdx.x;
    for (int i = tid; i < NB; i += 256) lc[i] = 0;
    __syncthreads();
    for (int e = blockIdx.x * 256 + tid; e < N_EDGES; e += gridDim.x * 256)
        atomicAdd(&lc[dst[e] >> 8], 1);
    __syncthreads();
    for (int i = tid; i < NB; i += 256)
        if (lc[i]) atomicAdd(&bucket_cnt[i], lc[i]);
}

// exclusive scan of bucket counts -> bucket_start[0..NB], gcursor
__global__ void bucket_scan_kernel(const int* __restrict__ bucket_cnt,
                                   int* __restrict__ bucket_start, int* __restrict__ gcur) {
    __shared__ int a[256];
    int tid = threadIdx.x;
    int v = (tid < NB) ? bucket_cnt[tid] : 0;
    a[tid] = v;
    __syncthreads();
    for (int off = 1; off < 256; off <<= 1) {
        int t = (tid >= off) ? a[tid - off] : 0;
        __syncthreads();
        a[tid] += t;
        __syncthreads();
    }
    int excl = a[tid] - v;
    if (tid < NB) { bucket_start[tid] = excl; gcur[tid] = excl; }
    if (tid == NB - 1) bucket_start[NB] = excl + v;
}

// ==================== sort pass 1: bin edges into coarse buckets ====================
__global__ __launch_bounds__(256) void pass1_kernel(const int* __restrict__ src,
                                                    const int* __restrict__ dst,
                                                    int* __restrict__ gcur,
                                                    unsigned* __restrict__ keys) {
    __shared__ int lcnt[NB], lbase[NB], lcnt2[NB];
    int tid = threadIdx.x;
    int e0 = blockIdx.x * CHUNK;
    unsigned k[CHUNK / 256];
    int bk[CHUNK / 256];
    for (int i = tid; i < NB; i += 256) lcnt[i] = 0;
    __syncthreads();
#pragma unroll
    for (int i = 0; i < CHUNK / 256; i++) {
        int e = e0 + i * 256 + tid;
        if (e < N_EDGES) {
            int d = dst[e];
            k[i] = ((unsigned)d << 16) | (unsigned)src[e];
            bk[i] = d >> 8;
            atomicAdd(&lcnt[bk[i]], 1);
        } else bk[i] = -1;
    }
    __syncthreads();
    for (int i = tid; i < NB; i += 256) {
        int c = lcnt[i];
        lbase[i] = c ? atomicAdd(&gcur[i], c) : 0;
        lcnt2[i] = 0;
    }
    __syncthreads();
#pragma unroll
    for (int i = 0; i < CHUNK / 256; i++) {
        if (bk[i] >= 0) {
            int r = atomicAdd(&lcnt2[bk[i]], 1);
            keys[lbase[bk[i]] + r] = k[i];
        }
    }
}

// ==================== per-node degree + per-bucket padded sums ====================
__global__ __launch_bounds__(256) void node_count_kernel(const unsigned* __restrict__ keys,
                                                         const int* __restrict__ bucket_start,
                                                         int* __restrict__ cnt,
                                                         int* __restrict__ bsum) {
    __shared__ int lc[256], rs[256];
    int tid = threadIdx.x, b = blockIdx.x;
    lc[tid] = 0;
    __syncthreads();
    int beg = bucket_start[b], end = bucket_start[b + 1];
    for (int p = beg + tid; p < end; p += 256)
        atomicAdd(&lc[(keys[p] >> 16) & 255], 1);
    __syncthreads();
    int node = b * 256 + tid;
    int c = (node < N_NODES) ? lc[tid] : 0;
    if (node < N_NODES) cnt[node] = c;
    rs[tid] = (c + 15) & ~15;
    __syncthreads();
    for (int off = 128; off > 0; off >>= 1) {
        if (tid < off) rs[tid] += rs[tid + off];
        __syncthreads();
    }
    if (tid == 0) bsum[b] = rs[0];
}

// exclusive scan of padded bucket sums -> bbase; writes row_start[N_NODES]
__global__ void pscan_kernel(const int* __restrict__ bsum, int* __restrict__ bbase,
                             int* __restrict__ row_start) {
    __shared__ int a[256];
    int tid = threadIdx.x;
    int v = (tid < NB) ? bsum[tid] : 0;
    a[tid] = v;
    __syncthreads();
    for (int off = 1; off < 256; off <<= 1) {
        int t = (tid >= off) ? a[tid - off] : 0;
        __syncthreads();
        a[tid] += t;
        __syncthreads();
    }
    int excl = a[tid] - v;
    if (tid < NB) bbase[tid] = excl;
    if (tid == NB - 1) row_start[N_NODES] = excl + v;
}

// ==================== pass 2: local scan -> row_start, block-local scatter + pad fill ============
__global__ __launch_bounds__(256) void pass2_kernel(const unsigned* __restrict__ keys,
                                                    const int* __restrict__ bucket_start,
                                                    const int* __restrict__ cnt,
                                                    const int* __restrict__ bbase,
                                                    int* __restrict__ row_start,
                                                    unsigned short* __restrict__ sorted_src) {
    __shared__ int loc[256], rs[256], cur[256];
    int tid = threadIdx.x, b = blockIdx.x;
    int node = b * 256 + tid;
    int c = (node < N_NODES) ? cnt[node] : 0;
    int pc = (c + 15) & ~15;
    loc[tid] = pc;
    cur[tid] = 0;
    __syncthreads();
    for (int off = 1; off < 256; off <<= 1) {
        int t = (tid >= off) ? loc[tid - off] : 0;
        __syncthreads();
        loc[tid] += t;
        __syncthreads();
    }
    int myrs = bbase[b] + loc[tid] - pc;  // exclusive
    rs[tid] = myrs;
    if (node < N_NODES) row_start[node] = myrs;
    __syncthreads();
    int beg = bucket_start[b], end = bucket_start[b + 1];
    for (int p = beg + tid; p < end; p += 256) {
        unsigned k = keys[p];
        int lidx = (k >> 16) & 255;
        int r = atomicAdd(&cur[lidx], 1);
        sorted_src[rs[lidx] + r] = (unsigned short)(k & 0xFFFFu);
    }
    __syncthreads();
    if (node < N_NODES) {
        int deg = cur[tid];
        if (deg > 0) {
            unsigned short s0 = sorted_src[myrs];
            for (int p = myrs + deg; p < myrs + pc; p++) sorted_src[p] = s0;  // max idempotent
        }
    }
}

// ============================ fc0: h0 = x @ fc0_w + fc0_b  (+ BN stats for block 0) ============
__global__ __launch_bounds__(256) void fc0_kernel(const float* __restrict__ x,
                                                  const float* __restrict__ w,
                                                  const float* __restrict__ b,
                                                  float* __restrict__ h0,
                                                  float* __restrict__ bns) {
    __shared__ float wl[F_IN * C];  // 32 KiB
    __shared__ __align__(16) float xr[4][F_IN];
    __shared__ float r1[4][64], r2[4][64];
    int tid = threadIdx.x, lane = tid & 63, wid = tid >> 6;
    for (int i = tid; i < F_IN * C; i += 256) wl[i] = w[i];
    __syncthreads();
    float bj = b[lane];
    float s1 = 0.f, s2 = 0.f;
    for (int n = blockIdx.x * 4 + wid; n < N_NODES; n += gridDim.x * 4) {
        xr[wid][lane]      = x[n * F_IN + lane];
        xr[wid][64 + lane] = x[n * F_IN + 64 + lane];
        const float4* x4 = (const float4*)xr[wid];
        float a0 = 0, a1 = 0, a2 = 0, a3 = 0;
#pragma unroll
        for (int k4 = 0; k4 < F_IN / 4; k4++) {
            float4 hv = x4[k4];
            a0 = fmaf(hv.x, wl[(4 * k4 + 0) * C + lane], a0);
            a1 = fmaf(hv.y, wl[(4 * k4 + 1) * C + lane], a1);
            a2 = fmaf(hv.z, wl[(4 * k4 + 2) * C + lane], a2);
            a3 = fmaf(hv.w, wl[(4 * k4 + 3) * C + lane], a3);
        }
        float v = (a0 + a1) + (a2 + a3) + bj;
        h0[n * C + lane] = v;
        s1 += v; s2 += v * v;
    }
    r1[wid][lane] = s1; r2[wid][lane] = s2;
    __syncthreads();
    if (tid < 64) {
        float a  = r1[0][tid] + r1[1][tid] + r1[2][tid] + r1[3][tid];
        float c2 = r2[0][tid] + r2[1][tid] + r2[2][tid] + r2[3][tid];
        int sl = blockIdx.x & (NSLICE - 1);
        atomicAdd(&bns[sl * 128 + tid], a);
        atomicAdd(&bns[sl * 128 + 64 + tid], c2);
    }
}

// ===== fold BN into effective edge-MLP layer-1 weights: WA = scale*(w1a-w1b), WB = scale*w1b =====
__global__ void prep_kernel(const float* __restrict__ bns, const float* __restrict__ g,
                            const float* __restrict__ bb, const float* __restrict__ w1,
                            const float* __restrict__ b1, float* __restrict__ WA,
                            float* __restrict__ WB, float* __restrict__ cAB) {
    __shared__ float scale[64], shift[64];
    int j = threadIdx.x;  // 64 threads
    float s1v = 0.f, s2v = 0.f;
#pragma unroll
    for (int s = 0; s < NSLICE; s++) { s1v += bns[s * 128 + j]; s2v += bns[s * 128 + 64 + j]; }
    float mu  = s1v * (1.0f / N_NODES);
    float var = s2v * (1.0f / N_NODES) - mu * mu;
    float sc  = g[j] * rsqrtf(var + EPS);
    scale[j] = sc;
    shift[j] = bb[j] - mu * sc;
    __syncthreads();
    float ca = b1[j], cb = 0.f;
    for (int k = 0; k < 64; k++) {
        float wa_ = w1[k * EF + j];
        float wb_ = w1[(64 + k) * EF + j];
        float wd  = wa_ - wb_;
        WA[k * 64 + j] = scale[k] * wd;
        WB[k * 64 + j] = scale[k] * wb_;
        ca += shift[k] * wd;
        cb += shift[k] * wb_;
    }
    cAB[j] = ca;
    cAB[64 + j] = cb;
}

// ============ per-node tables: A = h@WA + cA (f32), B = h@WB + cB (bf16) ============
__global__ __launch_bounds__(256) void ab_kernel(const float* __restrict__ h, int ldh,
                                                 const float* __restrict__ WA,
                                                 const float* __restrict__ WB,
                                                 const float* __restrict__ cAB,
                                                 float* __restrict__ A,
                                                 unsigned short* __restrict__ Bb) {
    __shared__ float wal[64 * 64], wbl[64 * 64];  // 32 KiB
    __shared__ __align__(16) float hr[4][64];
    int tid = threadIdx.x, lane = tid & 63, wid = tid >> 6;
    for (int i = tid; i < 4096; i += 256) { wal[i] = WA[i]; wbl[i] = WB[i]; }
    __syncthreads();
    float ca = cAB[lane], cb = cAB[64 + lane];
    for (int n = blockIdx.x * 4 + wid; n < N_NODES; n += gridDim.x * 4) {
        hr[wid][lane] = h[(size_t)n * ldh + lane];
        const float4* h4 = (const float4*)hr[wid];
        float accA = ca, accB = cb;
#pragma unroll
        for (int k4 = 0; k4 < 16; k4++) {
            float4 hv = h4[k4];
            accA = fmaf(hv.x, wal[(4 * k4 + 0) * 64 + lane], accA);
            accB = fmaf(hv.x, wbl[(4 * k4 + 0) * 64 + lane], accB);
            accA = fmaf(hv.y, wal[(4 * k4 + 1) * 64 + lane], accA);
            accB = fmaf(hv.y, wbl[(4 * k4 + 1) * 64 + lane], accB);
            accA = fmaf(hv.z, wal[(4 * k4 + 2) * 64 + lane], accA);
            accB = fmaf(hv.z, wbl[(4 * k4 + 2) * 64 + lane], accB);
            accA = fmaf(hv.w, wal[(4 * k4 + 3) * 64 + lane], accA);
            accB = fmaf(hv.w, wbl[(4 * k4 + 3) * 64 + lane], accB);
        }
        A[n * 64 + lane] = accA;
        Bb[n * 64 + lane] = (unsigned short)((__float_as_uint(accB) + 0x8000u) >> 16);
    }
}

// ============ EdgeConv via MFMA, static scheduling, 2-tile ILP, packed math ============
__global__ __launch_bounds__(256, 4) void edge_mfma_kernel(
        const float* __restrict__ A, const unsigned short* __restrict__ Bb,
        const int* __restrict__ row_start, const unsigned short* __restrict__ sorted_src,
        const float* __restrict__ w2, const float* __restrict__ b2,
        float* __restrict__ cat, int colofs, float* __restrict__ bnsNext) {
    __shared__ float r1[4][64], r2[4][64];
    int tid = threadIdx.x, lane = tid & 63, wid = tid >> 6;
    int kq = (lane >> 4) * 8;  // this lane's k-offset within each 32-chunk
    int cl = lane & 15;

    // w2 fragments, wave-invariant, held in registers (16 VGPRs)
    short8 bfr[2][4];
#pragma unroll
    for (int kh = 0; kh < 2; kh++)
#pragma unroll
        for (int cb = 0; cb < 4; cb++) {
            union { short8 s; unsigned u[4]; } f;
#pragma unroll
            for (int j = 0; j < 4; j++) {
                float w0 = w2[(kh * 32 + kq + 2 * j) * 64 + cb * 16 + cl];
                float w1 = w2[(kh * 32 + kq + 2 * j + 1) * 64 + cb * 16 + cl];
                f.u[j] = pack2bf(w0, w1);
            }
            bfr[kh][cb] = f.s;
        }
    float b2j = b2[lane];
    float s1 = 0.f, s2 = 0.f;
    const floatx2 zero2 = {0.f, 0.f};

    for (int n = blockIdx.x * 4 + wid; n < N_NODES; n += gridDim.x * 4) {
        int beg = row_start[n], end = row_start[n + 1];
        const float* arow = A + (size_t)n * 64 + kq;
        floatx4 t0 = *(const floatx4*)(arow);
        floatx4 t1 = *(const floatx4*)(arow + 4);
        floatx4 t2 = *(const floatx4*)(arow + 32);
        floatx4 t3 = *(const floatx4*)(arow + 36);
        floatx2 aj0[4], aj1[4];
        aj0[0] = floatx2{t0.x, t0.y}; aj0[1] = floatx2{t0.z, t0.w};
        aj0[2] = floatx2{t1.x, t1.y}; aj0[3] = floatx2{t1.z, t1.w};
        aj1[0] = floatx2{t2.x, t2.y}; aj1[1] = floatx2{t2.z, t2.w};
        aj1[2] = floatx2{t3.x, t3.y}; aj1[3] = floatx2{t3.z, t3.w};
        floatx4 rmax0 = {-INFINITY, -INFINITY, -INFINITY, -INFINITY};
        floatx4 rmax1 = rmax0, rmax2 = rmax0, rmax3 = rmax0;

        // one 16-edge tile: from preloaded bf16 rows u0/u1 -> relu(A+B) -> 8 MFMAs -> rmax
        auto tile = [&](uintx4 u0, uintx4 u1) {
            union { short8 s; unsigned u[4]; } a0, a1;
#pragma unroll
            for (int j = 0; j < 4; j++) {
                floatx2 s0 = floatx2{__uint_as_float(u0[j] << 16),
                                     __uint_as_float(u0[j] & 0xFFFF0000u)} + aj0[j];
                floatx2 sx = floatx2{__uint_as_float(u1[j] << 16),
                                     __uint_as_float(u1[j] & 0xFFFF0000u)} + aj1[j];
                s0 = __builtin_elementwise_max(s0, zero2);
                sx = __builtin_elementwise_max(sx, zero2);
                a0.u[j] = pack2bf(s0.x, s0.y);
                a1.u[j] = pack2bf(sx.x, sx.y);
            }
            floatx4 acc0 = {0.f, 0.f, 0.f, 0.f}, acc1 = acc0, acc2 = acc0, acc3 = acc0;
            acc0 = __builtin_amdgcn_mfma_f32_16x16x32_bf16(a0.s, bfr[0][0], acc0, 0, 0, 0);
            acc1 = __builtin_amdgcn_mfma_f32_16x16x32_bf16(a0.s, bfr[0][1], acc1, 0, 0, 0);
            acc2 = __builtin_amdgcn_mfma_f32_16x16x32_bf16(a0.s, bfr[0][2], acc2, 0, 0, 0);
            acc3 = __builtin_amdgcn_mfma_f32_16x16x32_bf16(a0.s, bfr[0][3], acc3, 0, 0, 0);
            acc0 = __builtin_amdgcn_mfma_f32_16x16x32_bf16(a1.s, bfr[1][0], acc0, 0, 0, 0);
            acc1 = __builtin_amdgcn_mfma_f32_16x16x32_bf16(a1.s, bfr[1][1], acc1, 0, 0, 0);
            acc2 = __builtin_amdgcn_mfma_f32_16x16x32_bf16(a1.s, bfr[1][2], acc2, 0, 0, 0);
            acc3 = __builtin_amdgcn_mfma_f32_16x16x32_bf16(a1.s, bfr[1][3], acc3, 0, 0, 0);
            rmax0 = __builtin_elementwise_max(rmax0, acc0);
            rmax1 = __builtin_elementwise_max(rmax1, acc1);
            rmax2 = __builtin_elementwise_max(rmax2, acc2);
            rmax3 = __builtin_elementwise_max(rmax3, acc3);
        };
        auto gather = [&](int p, uintx4& u0, uintx4& u1) {
            int srcm = sorted_src[p + cl];
            const unsigned short* brow = Bb + (size_t)srcm * 64 + kq;
            u0 = *(const uintx4*)(brow);
            u1 = *(const uintx4*)(brow + 32);
        };

        int p0 = beg;
        for (; p0 + 32 <= end; p0 += 32) {   // two tiles per iter: both gathers in flight
            uintx4 x0, x1, y0, y1;
            gather(p0, x0, x1);
            gather(p0 + 16, y0, y1);
            tile(x0, x1);
            tile(y0, y1);
        }
        if (p0 < end) {                       // odd-tile remainder
            uintx4 x0, x1;
            gather(p0, x0, x1);
            tile(x0, x1);
        }

        float v0 = fmaxf(fmaxf(rmax0.x, rmax0.y), fmaxf(rmax0.z, rmax0.w));
        float v1 = fmaxf(fmaxf(rmax1.x, rmax1.y), fmaxf(rmax1.z, rmax1.w));
        float v2 = fmaxf(fmaxf(rmax2.x, rmax2.y), fmaxf(rmax2.z, rmax2.w));
        float v3 = fmaxf(fmaxf(rmax3.x, rmax3.y), fmaxf(rmax3.z, rmax3.w));
        v0 = fmaxf(v0, __shfl_xor(v0, 16)); v0 = fmaxf(v0, __shfl_xor(v0, 32));
        v1 = fmaxf(v1, __shfl_xor(v1, 16)); v1 = fmaxf(v1, __shfl_xor(v1, 32));
        v2 = fmaxf(v2, __shfl_xor(v2, 16)); v2 = fmaxf(v2, __shfl_xor(v2, 32));
        v3 = fmaxf(v3, __shfl_xor(v3, 16)); v3 = fmaxf(v3, __shfl_xor(v3, 32));
        float vs = (lane & 32) ? ((lane & 16) ? v3 : v2) : ((lane & 16) ? v1 : v0);
        float v = fmaxf(vs + b2j, 0.f);  // -inf (empty node) -> 0; folds where(isfinite)+relu
        cat[(size_t)n * 192 + colofs + lane] = v;
        s1 += v; s2 += v * v;
    }

    if (bnsNext) {
        r1[wid][lane] = s1; r2[wid][lane] = s2;
        __syncthreads();
        if (tid < 64) {
            float a  = r1[0][tid] + r1[1][tid] + r1[2][tid] + r1[3][tid];
            float c2 = r2[0][tid] + r2[1][tid] + r2[2][tid] + r2[3][tid];
            int sl = blockIdx.x & (NSLICE - 1);
            atomicAdd(&bnsNext[sl * 128 + tid], a);
            atomicAdd(&bnsNext[sl * 128 + 64 + tid], c2);
        }
    }
}

// ============================ fused graph mean pool + MLP head + log_softmax ============================
__global__ __launch_bounds__(192) void poolhead_kernel(const float* __restrict__ cat,
                                                       const int* __restrict__ batch,
                                                       const float* __restrict__ fc1w,
                                                       const float* __restrict__ fc1b,
                                                       const float* __restrict__ fc2w,
                                                       const float* __restrict__ fc2b,
                                                       float* __restrict__ out) {
    __shared__ int se[2];
    __shared__ float p[192];
    __shared__ float hid[128];
    __shared__ float z[10];
    __shared__ float lse;
    int g = blockIdx.x, tid = threadIdx.x;  // 192 threads
    if (tid < 2) {
        int target = g + tid;
        int lo = 0, hi = N_NODES;
        while (lo < hi) { int mid = (lo + hi) >> 1; if (batch[mid] < target) lo = mid + 1; else hi = mid; }
        se[tid] = lo;
    }
    __syncthreads();
    int s = se[0], e = se[1];
    float acc = 0.f;
    for (int r = s; r < e; r++) acc += cat[(size_t)r * 192 + tid];
    float denom = (e > s) ? (float)(e - s) : 1.0f;
    p[tid] = acc / denom;
    __syncthreads();
    if (tid < MLP_DIM) {
        float a = fc1b[tid];
        for (int k = 0; k < 192; k++) a = fmaf(p[k], fc1w[k * 128 + tid], a);
        hid[tid] = fmaxf(a, 0.f);
    }
    __syncthreads();
    if (tid < N_CLASSES) {
        float a = fc2b[tid];
        for (int k = 0; k < 128; k++) a = fmaf(hid[k], fc2w[k * 10 + tid], a);
        z[tid] = a;
    }
    __syncthreads();
    if (tid == 0) {
        float m = z[0];
        for (int i = 1; i < 10; i++) m = fmaxf(m, z[i]);
        float sm = 0.f;
        for (int i = 0; i < 10; i++) sm += expf(z[i] - m);
        lse = m + logf(sm);
    }
    __syncthreads();
    if (tid < N_CLASSES) out[g * 10 + tid] = z[tid] - lse;
}

// ============================ launch ============================
extern "C" void kernel_launch(void* const* d_in, const int* in_sizes, int n_in,
                              void* d_out, int out_size, void* d_ws, size_t ws_size,
                              hipStream_t stream) {
    (void)in_sizes; (void)n_in; (void)out_size; (void)ws_size;
    const float* x    = (const float*)d_in[0];
    const int*   ei   = (const int*)d_in[1];
    const int*   batch= (const int*)d_in[2];
    const float* fc0w = (const float*)d_in[3];
    const float* fc0b = (const float*)d_in[4];
    const float* fc1w = (const float*)d_in[5];
    const float* fc1b = (const float*)d_in[6];
    const float* fc2w = (const float*)d_in[7];
    const float* fc2b = (const float*)d_in[8];
    const int* src = ei;
    const int* dst = ei + N_EDGES;
    float* out = (float*)d_out;

    char* w = (char*)d_ws;
    size_t off = 0;
    auto alloc = [&](size_t bytes) -> void* {
        void* p = w + off;
        off = (off + bytes + 255) & ~(size_t)255;
        return p;
    };
    const size_t MAX_PAD_EDGES = (size_t)N_EDGES + 16 * (size_t)N_NODES;

    // zeroed-every-launch block: bucket_cnt | bns[3][NSLICE][128]
    char* zbase = (char*)alloc(1024 + 3 * NSLICE * 128 * 4);
    int*   bucket_cnt = (int*)zbase;                 // NB ints
    float* bnsAll = (float*)(zbase + 1024);          // 3 * NSLICE * 128 floats
    const size_t ZBYTES = 1024 + 3 * NSLICE * 128 * 4;

    float* cat     = (float*)alloc((size_t)N_NODES * 192 * 4);   // 38.4 MB
    float* h0      = (float*)alloc((size_t)N_NODES * 64 * 4);    // 12.8 MB
    float* Ae      = (float*)alloc((size_t)N_NODES * 64 * 4);    // 12.8 MB
    unsigned short* Be = (unsigned short*)alloc((size_t)N_NODES * 64 * 2);  // 6.4 MB (bf16)
    unsigned* keys = (unsigned*)alloc((size_t)N_EDGES * 4);      // 6.4 MB
    unsigned short* sorted_src = (unsigned short*)alloc(MAX_PAD_EDGES * 2);  // 4.8 MB
    int*   cnt     = (int*)alloc((size_t)N_NODES * 4);
    int*   row_start = (int*)alloc((size_t)(N_NODES + 1) * 4);
    int*   bucket_start = (int*)alloc((NB + 1) * 4);
    int*   gcur    = (int*)alloc(NB * 4);
    int*   bsum    = (int*)alloc(NB * 4);
    int*   bbase   = (int*)alloc(NB * 4);
    float* WA      = (float*)alloc(4096 * 4);
    float* WB      = (float*)alloc(4096 * 4);
    float* cAB     = (float*)alloc(128 * 4);

    hipMemsetAsync(zbase, 0, ZBYTES, stream);

    // --- two-level counting sort: edges -> padded CSR by dst ---
    precount_kernel<<<256, 256, 0, stream>>>(dst, bucket_cnt);
    bucket_scan_kernel<<<1, 256, 0, stream>>>(bucket_cnt, bucket_start, gcur);
    pass1_kernel<<<(N_EDGES + CHUNK - 1) / CHUNK, 256, 0, stream>>>(src, dst, gcur, keys);
    node_count_kernel<<<NB, 256, 0, stream>>>(keys, bucket_start, cnt, bsum);
    pscan_kernel<<<1, 256, 0, stream>>>(bsum, bbase, row_start);
    pass2_kernel<<<NB, 256, 0, stream>>>(keys, bucket_start, cnt, bbase, row_start, sorted_src);

    fc0_kernel<<<1024, 256, 0, stream>>>(x, fc0w, fc0b, h0, bnsAll);

    for (int blk = 0; blk < 3; blk++) {
        const float* g  = (const float*)d_in[9 + 6 * blk];
        const float* bb = (const float*)d_in[10 + 6 * blk];
        const float* w1 = (const float*)d_in[11 + 6 * blk];
        const float* b1 = (const float*)d_in[12 + 6 * blk];
        const float* w2 = (const float*)d_in[13 + 6 * blk];
        const float* b2 = (const float*)d_in[14 + 6 * blk];
        const float* hsrc = (blk == 0) ? h0 : (cat + (blk - 1) * 64);
        int ldh = (blk == 0) ? 64 : 192;

        prep_kernel<<<1, 64, 0, stream>>>(bnsAll + blk * NSLICE * 128, g, bb, w1, b1, WA, WB, cAB);
        ab_kernel<<<1024, 256, 0, stream>>>(hsrc, ldh, WA, WB, cAB, Ae, Be);
        edge_mfma_kernel<<<1024, 256, 0, stream>>>(
            Ae, Be, row_start, sorted_src, w2, b2, cat, blk * 64,
            (blk < 2) ? (bnsAll + (blk + 1) * NSLICE * 128) : nullptr);
    }

    poolhead_kernel<<<N_GRAPHS, 192, 0, stream>>>(cat, batch, fc1w, fc1b, fc2w, fc2b, out);
}